// Round 8
// baseline (286.597 us; speedup 1.0000x reference)
//
#include <hip/hip_runtime.h>
#include <hip/hip_bf16.h>
#include <cstdint>
#include <cstddef>

#define DM 2048
#define DG 512
#define NBATCH 4
#define NT 4096
#define NM (NBATCH*NT)     // 16384 rows
#define KC (2*DM)          // 4096 concat-K (i8 elems = bytes)
#define LN_EPS 1e-5f
#define NTILES (KC/128)    // 32 K-tiles of BK=128 i8
#define SCL_A 16.0f        // qA = rint(x*16), covers |x|<=7.94
#define SCL_B 8192.0f      // qB = rint(w*8192), covers |w|<=0.0155
#define DESCALE (1.0f/131072.0f)   // 1/(SCL_A*SCL_B)

typedef __bf16 bf16;
typedef bf16 bf16x8 __attribute__((ext_vector_type(8)));
typedef float f32x4 __attribute__((ext_vector_type(4)));
typedef int   i32x4 __attribute__((ext_vector_type(4)));
typedef char  i8x8  __attribute__((ext_vector_type(8)));
typedef char  i8x16 __attribute__((ext_vector_type(16)));
typedef unsigned char u8x8 __attribute__((ext_vector_type(8)));

#define AS1 __attribute__((address_space(1)))
#define AS3 __attribute__((address_space(3)))

__device__ __forceinline__ char q8(float x, float s) {
    int v = (int)rintf(x * s);
    v = v > 127 ? 127 : (v < -127 ? -127 : v);
    return (char)v;
}

// ---------- block-wide sum reduction of two scalars (blockDim.x == 256) ----------
__device__ __forceinline__ void block_reduce_2(float& s, float& s2) {
#pragma unroll
    for (int off = 32; off; off >>= 1) {
        s  += __shfl_down(s, off);
        s2 += __shfl_down(s2, off);
    }
    __shared__ float sm[8];
    const int wid = threadIdx.x >> 6, lane = threadIdx.x & 63;
    if (lane == 0) { sm[wid] = s; sm[4 + wid] = s2; }
    __syncthreads();
    s  = sm[0] + sm[1] + sm[2] + sm[3];
    s2 = sm[4] + sm[5] + sm[6] + sm[7];
}

// ---------- quantize + fragment-pack w_gate (f32 [DM][KC]) -> i8 PB ----------
// unit t <-> (col16 = t>>12, kt = (t>>7)&31, ks = (t>>6)&1, lane = t&63); 16 i8/unit.
// PB[t*16 + e] = q8(w[(col16*16 + (lane&15))][kt*128 + ks*64 + (lane>>4)*16 + e])
__global__ void k_pack_i8(const float* __restrict__ src, int8_t* __restrict__ dst) {
    int t = blockIdx.x * blockDim.x + threadIdx.x;   // 524288 units
    const int lane = t & 63, ks = (t >> 6) & 1, kt = (t >> 7) & 31, col16 = t >> 12;
    const int row = col16 * 16 + (lane & 15);
    const int k0  = kt * 128 + ks * 64 + (lane >> 4) * 16;
    const f32x4* s = (const f32x4*)(src + (size_t)row * KC + k0);
    f32x4 a = s[0], b = s[1], c = s[2], d = s[3];
    i8x16 o;
#pragma unroll
    for (int q = 0; q < 4; q++) {
        o[q] = q8(a[q], SCL_B); o[4+q] = q8(b[q], SCL_B);
        o[8+q] = q8(c[q], SCL_B); o[12+q] = q8(d[q], SCL_B);
    }
    *((i8x16*)dst + t) = o;
}

// ---------- small GEMV: out[b][j] = dot(X[b,:K], W[j,:K]) + bias[j] ----------
template<int K>
__global__ void k_dot(const float* __restrict__ X, const float* __restrict__ W,
                      const float* __restrict__ bias, float* __restrict__ out) {
    const int lane = threadIdx.x & 63;
    const int wid  = threadIdx.x >> 6;
    const int j = blockIdx.x * 4 + wid;
    const f32x4* Wr = (const f32x4*)(W + (size_t)j * K);
    float acc[NBATCH] = {0.f, 0.f, 0.f, 0.f};
    constexpr int C = K / 4 / 64;
#pragma unroll
    for (int i = 0; i < C; i++) {
        f32x4 wv = Wr[lane + 64 * i];
#pragma unroll
        for (int b = 0; b < NBATCH; b++) {
            f32x4 xv = ((const f32x4*)(X + (size_t)b * K))[lane + 64 * i];
            acc[b] += wv[0]*xv[0] + wv[1]*xv[1] + wv[2]*xv[2] + wv[3]*xv[3];
        }
    }
#pragma unroll
    for (int off = 32; off; off >>= 1)
#pragma unroll
        for (int b = 0; b < NBATCH; b++) acc[b] += __shfl_down(acc[b], off);
    if (lane == 0) {
        const float bb = bias[j];
#pragma unroll
        for (int b = 0; b < NBATCH; b++) out[(size_t)b * DM + j] = acc[b] + bb;
    }
}

// ---------- LN over rows of [NBATCH][DM] ----------
__global__ void k_ln_small(const float* __restrict__ in, const float* __restrict__ g,
                           const float* __restrict__ bt, float* __restrict__ out) {
    const int row = blockIdx.x;
    const int tid = threadIdx.x;
    const f32x4* ir = (const f32x4*)(in + (size_t)row * DM);
    f32x4 v0 = ir[tid], v1 = ir[tid + 256];
    float s  = v0[0]+v0[1]+v0[2]+v0[3] + v1[0]+v1[1]+v1[2]+v1[3];
    float s2 = v0[0]*v0[0]+v0[1]*v0[1]+v0[2]*v0[2]+v0[3]*v0[3]
             + v1[0]*v1[0]+v1[1]*v1[1]+v1[2]*v1[2]+v1[3]*v1[3];
    block_reduce_2(s, s2);
    const float mu = s * (1.0f / DM);
    const float r  = rsqrtf(s2 * (1.0f / DM) - mu * mu + LN_EPS);
    f32x4 g0 = ((const f32x4*)g)[tid],  g1v = ((const f32x4*)g)[tid + 256];
    f32x4 b0 = ((const f32x4*)bt)[tid], b1v = ((const f32x4*)bt)[tid + 256];
    f32x4 o0 = (v0 - mu) * r * g0 + b0;
    f32x4 o1 = (v1 - mu) * r * g1v + b1v;
    f32x4* orow = (f32x4*)(out + (size_t)row * DM);
    orow[tid] = o0; orow[tid + 256] = o1;
}

// ---------- per-row stats of (h+attn); write i8 [h | attn_out] + bf16 h copy ----------
__global__ void k_stats_pack(const float* __restrict__ h, const float* __restrict__ attnv,
                             const float* __restrict__ g2, const float* __restrict__ b2,
                             int8_t* __restrict__ Aq, bf16* __restrict__ hbf,
                             float* __restrict__ muA, float* __restrict__ rA) {
    const int m = blockIdx.x;
    const int b = m >> 12;
    const int tid = threadIdx.x;          // thread covers elems [8*tid, 8*tid+8)
    const f32x4* hr = (const f32x4*)(h + (size_t)m * DM);
    const f32x4* ar = (const f32x4*)(attnv + (size_t)b * DM);
    f32x4 h0 = hr[2*tid], h1 = hr[2*tid + 1];
    f32x4 a0 = ar[2*tid], a1 = ar[2*tid + 1];
    f32x4 x0 = h0 + a0, x1 = h1 + a1;
    float s  = x0[0]+x0[1]+x0[2]+x0[3] + x1[0]+x1[1]+x1[2]+x1[3];
    float s2 = x0[0]*x0[0]+x0[1]*x0[1]+x0[2]*x0[2]+x0[3]*x0[3]
             + x1[0]*x1[0]+x1[1]*x1[1]+x1[2]*x1[2]+x1[3]*x1[3];
    block_reduce_2(s, s2);
    const float mu = s * (1.0f / DM);
    const float r  = rsqrtf(s2 * (1.0f / DM) - mu * mu + LN_EPS);
    if (tid == 0) { muA[m] = mu; rA[m] = r; }
    f32x4 gg0 = ((const f32x4*)g2)[2*tid], gg1 = ((const f32x4*)g2)[2*tid + 1];
    f32x4 bb0 = ((const f32x4*)b2)[2*tid], bb1 = ((const f32x4*)b2)[2*tid + 1];
    f32x4 ao0 = (x0 - mu) * r * gg0 + bb0;
    f32x4 ao1 = (x1 - mu) * r * gg1 + bb1;
    bf16x8 hv;
#pragma unroll
    for (int q = 0; q < 4; q++) { hv[q] = (bf16)h0[q]; hv[4+q] = (bf16)h1[q]; }
    *(bf16x8*)(hbf + (size_t)m * DM + 8*tid) = hv;
    i8x8 qh, qa;
#pragma unroll
    for (int q = 0; q < 4; q++) {
        qh[q] = q8(h0[q], SCL_A);  qh[4+q] = q8(h1[q], SCL_A);
        qa[q] = q8(ao0[q], SCL_A); qa[4+q] = q8(ao1[q], SCL_A);
    }
    *(i8x8*)(Aq + (size_t)m * KC + 8*tid) = qh;
    *(i8x8*)(Aq + (size_t)m * KC + DM + 8*tid) = qa;
}

// ---------- 256x256 i8 MFMA GEMM v8: A-only LDS + B fragment-packed direct-to-reg ----------
// LDS/tile drops 256KB -> 160KB (below the MFMA floor). B frags rotate in-register
// (b01 reloaded after Q2, b23 after Q3). Audited vmcnt ledger:
//   enter T: [b01(T)4, b23(T)4]; S3 VM(6) retires b01; S6 VM(4) retires b23;
//   S9 VM(8) retires the 4 A-stages; BAR. r2 XCD swizzle kept (FETCH-verified).
#define MF(a,b,c) __builtin_amdgcn_mfma_i32_16x16x64_i8(a,b,c,0,0,0)
#define SCHED0() __builtin_amdgcn_sched_barrier(0)
#define BAR()  { SCHED0(); asm volatile("s_barrier" ::: "memory"); SCHED0(); }
#define VM(n)  { asm volatile("s_waitcnt vmcnt(" #n ")" ::: "memory"); SCHED0(); }
#define LGKM(n) { asm volatile("s_waitcnt lgkmcnt(" #n ")" ::: "memory"); SCHED0(); }

__global__ __launch_bounds__(512, 2) void k_gemm256(const int8_t* __restrict__ A, const int8_t* __restrict__ PB,
                                                    const float* __restrict__ bgate, uint8_t* __restrict__ gq) {
    __shared__ __align__(128) char smem[65536];   // [2 bufs][4 rounds][8KB] — A only
    const int tid  = threadIdx.x;
    const int lane = tid & 63;
    const int wid  = tid >> 6;
    const int wm   = wid >> 2, wn = wid & 3;

    // bijective XCD swizzle (r2/r7 mapping, FETCH-verified): 512 blocks, 8 XCDs
    const int swz = (blockIdx.x & 7) * 64 + (blockIdx.x >> 3);
    const int bm = (swz >> 3) << 8;
    const int bn = (swz & 7) << 8;

    // A staging: inverse-swizzled global source (bytes), linear LDS dest
    const int r_local = tid >> 3;                 // row within a 64-row round
    const int sc = (tid & 7) ^ (r_local & 7);     // swizzled 16B chunk
    const int8_t* Abase = A + (size_t)(bm + r_local) * KC + sc*16;
    const int ldsW = wid << 10;

#define STAGEA(buf, rnd, kt) __builtin_amdgcn_global_load_lds( \
        (const AS1 void*)(Abase + (size_t)(rnd)*64*KC + (kt)*128), \
        (AS3 void*)(smem + (buf)*32768 + (rnd)*8192 + ldsW), 16, 0, 0)

    // A fragment read byte offsets (swizzled); rows are 128B
    const int co0 = ((lane >> 4) ^ (lane & 7)) << 4;         // ks=0: k 0..63
    const int co1 = ((4 + (lane >> 4)) ^ (lane & 7)) << 4;   // ks=1: k 64..127
    const int arowb = (wm*128 + (lane & 15)) * 128;

#define AFRG(buf, m, ks) (*(const i32x4*)(smem + (buf)*32768 + arowb + (m)*2048 + ((ks) ? co1 : co0)))

    // B packed pointers: frag col16 = bn/16 + wn*4 + n; per (kt,ks): + kt*2048 + ks*1024
    const int8_t* PBp[4];
#pragma unroll
    for (int n = 0; n < 4; n++)
        PBp[n] = PB + (size_t)((bn >> 4) + wn * 4 + n) * 65536 + lane * 16;

    i32x4 acc[8][4] = {};
    i32x4 aLo[4][2], aHi[4][2], b01[2][2], b23[2][2];

#define LOAD_ALO(buf) { _Pragma("unroll") for (int i = 0; i < 4; i++) { aLo[i][0] = AFRG(buf,i,0);   aLo[i][1] = AFRG(buf,i,1);   } }
#define LOAD_AHI(buf) { _Pragma("unroll") for (int i = 0; i < 4; i++) { aHi[i][0] = AFRG(buf,4+i,0); aHi[i][1] = AFRG(buf,4+i,1); } }
#define LOADB01(kt) { _Pragma("unroll") for (int j = 0; j < 2; j++) { \
        b01[j][0] = *(const i32x4*)(PBp[j]   + (kt)*2048);        \
        b01[j][1] = *(const i32x4*)(PBp[j]   + (kt)*2048 + 1024); } }
#define LOADB23(kt) { _Pragma("unroll") for (int j = 0; j < 2; j++) { \
        b23[j][0] = *(const i32x4*)(PBp[2+j] + (kt)*2048);        \
        b23[j][1] = *(const i32x4*)(PBp[2+j] + (kt)*2048 + 1024); } }

#define MMQ(MOFF, AF, BF, NOFF) { _Pragma("unroll") for (int i = 0; i < 4; i++) \
        _Pragma("unroll") for (int j = 0; j < 2; j++) { \
            acc[(MOFF)+i][(NOFF)+j] = MF(AF[i][0], BF[j][0], acc[(MOFF)+i][(NOFF)+j]); \
            acc[(MOFF)+i][(NOFF)+j] = MF(AF[i][1], BF[j][1], acc[(MOFF)+i][(NOFF)+j]); } }

    // ---- prologue: A(tile0)->buf0, b01(0), b23(0); retire stages; BAR
    STAGEA(0,0,0); STAGEA(0,1,0); STAGEA(0,2,0); STAGEA(0,3,0);
    LOADB01(0);
    LOADB23(0);
    VM(8);
    BAR();

    // quadrants: Q0=(aLo,b01)->acc[0-3][0-1], Q1=(aLo,b23)->acc[0-3][2-3],
    //            Q2=(aHi,b01)->acc[4-7][0-1], Q3=(aHi,b23)->acc[4-7][2-3]
#define TILE_BODY(TT, BUF, NBUF) { \
    const bool g = (TT) < NTILES - 1; \
    /* S1-S4: stage A0,A2(T+1); read aLo; retire b01(T); Q0 */ \
    if (g) { STAGEA(NBUF,0,(TT)+1); STAGEA(NBUF,2,(TT)+1); } \
    LOAD_ALO(BUF); SCHED0(); \
    if (g) { VM(6); } else { VM(4); } \
    LGKM(0); \
    __builtin_amdgcn_s_setprio(1); \
    MMQ(0, aLo, b01, 0); \
    __builtin_amdgcn_s_setprio(0); SCHED0(); \
    /* S5-S6: stage A1,A3(T+1); issue aHi ahead; retire b23(T); Q1 */ \
    if (g) { STAGEA(NBUF,1,(TT)+1); STAGEA(NBUF,3,(TT)+1); } \
    LOAD_AHI(BUF); SCHED0(); \
    if (g) { VM(4); } else { VM(0); } \
    __builtin_amdgcn_s_setprio(1); \
    MMQ(0, aLo, b23, 2); \
    __builtin_amdgcn_s_setprio(0); SCHED0(); \
    /* S7: Q2 (aHi drained under Q1); then reload b01 <- T+1 */ \
    LGKM(0); \
    __builtin_amdgcn_s_setprio(1); \
    MMQ(4, aHi, b01, 0); \
    __builtin_amdgcn_s_setprio(0); \
    if (g) { LOADB01((TT)+1); } SCHED0(); \
    /* S8: Q3; then reload b23 <- T+1 */ \
    __builtin_amdgcn_s_setprio(1); \
    MMQ(4, aHi, b23, 2); \
    __builtin_amdgcn_s_setprio(0); \
    if (g) { LOADB23((TT)+1); } SCHED0(); \
    /* S9: retire A-stages(T+1); publish */ \
    if (g) { VM(8); } \
    BAR(); \
}

    for (int T = 0; T < NTILES; T += 2) {
        TILE_BODY(T,   0, 1);
        TILE_BODY(T+1, 1, 0);
    }

    // ---- epilogue: gate = sigmoid(acc*DESCALE + bias) -> u8
#pragma unroll
    for (int n = 0; n < 4; n++) {
        const int col = bn + wn*64 + n*16 + (lane & 15);
        const float bg = bgate[col];
#pragma unroll
        for (int m = 0; m < 8; m++) {
            const int row = bm + wm*128 + m*16 + ((lane >> 4) << 2);
#pragma unroll
            for (int r = 0; r < 4; r++) {
                const float z = (float)acc[m][n][r] * DESCALE + bg;
                const float gate = 1.0f / (1.0f + __expf(-z));
                gq[(size_t)(row + r) * DM + col] = (uint8_t)(int)rintf(gate * 255.0f);
            }
        }
    }
}

// ---------- epilogue: blend with u8 gate, LN3 per row ----------
__global__ void k_epilogue(const bf16* __restrict__ hbf, const uint8_t* __restrict__ gq,
                           const float* __restrict__ attnv, const float* __restrict__ muA,
                           const float* __restrict__ rA,
                           const float* __restrict__ g2, const float* __restrict__ b2,
                           const float* __restrict__ g3, const float* __restrict__ b3,
                           float* __restrict__ out) {
    const int m = blockIdx.x;
    const int b = m >> 12;
    const int tid = threadIdx.x;          // thread handles elems [8*tid, 8*tid+8)
    bf16x8 hb = *(const bf16x8*)(hbf + (size_t)m * DM + 8*tid);
    f32x4 h0, h1;
#pragma unroll
    for (int q = 0; q < 4; q++) { h0[q] = (float)hb[q]; h1[q] = (float)hb[4+q]; }
    const f32x4* ar = (const f32x4*)(attnv + (size_t)b * DM);
    f32x4 a0 = ar[2*tid], a1 = ar[2*tid + 1];
    const float mu = muA[m];
    const float r  = rA[m];
    f32x4 gg0 = ((const f32x4*)g2)[2*tid], gg1 = ((const f32x4*)g2)[2*tid + 1];
    f32x4 bb0 = ((const f32x4*)b2)[2*tid], bb1 = ((const f32x4*)b2)[2*tid + 1];
    f32x4 ao0 = (h0 + a0 - mu) * r * gg0 + bb0;
    f32x4 ao1 = (h1 + a1 - mu) * r * gg1 + bb1;
    u8x8 qv = *(const u8x8*)(gq + (size_t)m * DM + 8*tid);
    f32x4 gt0, gt1;
#pragma unroll
    for (int q = 0; q < 4; q++) {
        gt0[q] = (float)qv[q]   * (1.0f / 255.0f);
        gt1[q] = (float)qv[4+q] * (1.0f / 255.0f);
    }
    f32x4 f0 = h0 + gt0 * (ao0 - h0);
    f32x4 f1 = h1 + gt1 * (ao1 - h1);
    float s  = f0[0]+f0[1]+f0[2]+f0[3] + f1[0]+f1[1]+f1[2]+f1[3];
    float s2 = f0[0]*f0[0]+f0[1]*f0[1]+f0[2]*f0[2]+f0[3]*f0[3]
             + f1[0]*f1[0]+f1[1]*f1[1]+f1[2]*f1[2]+f1[3]*f1[3];
    block_reduce_2(s, s2);
    const float mu3 = s * (1.0f / DM);
    const float r3  = rsqrtf(s2 * (1.0f / DM) - mu3 * mu3 + LN_EPS);
    f32x4 g30 = ((const f32x4*)g3)[2*tid], g31 = ((const f32x4*)g3)[2*tid + 1];
    f32x4 b30 = ((const f32x4*)b3)[2*tid], b31 = ((const f32x4*)b3)[2*tid + 1];
    f32x4 o0 = (f0 - mu3) * r3 * g30 + b30;
    f32x4 o1 = (f1 - mu3) * r3 * g31 + b31;
    f32x4* orow = (f32x4*)(out + (size_t)m * DM);
    orow[2*tid] = o0; orow[2*tid + 1] = o1;
}

extern "C" void kernel_launch(void* const* d_in, const int* in_sizes, int n_in,
                              void* d_out, int out_size, void* d_ws, size_t ws_size,
                              hipStream_t stream) {
    const float* h_llm    = (const float*)d_in[0];
    const float* h_change = (const float*)d_in[1];
    const float* w_proj   = (const float*)d_in[2];
    const float* b_proj   = (const float*)d_in[3];
    const float* g1       = (const float*)d_in[4];
    const float* b1       = (const float*)d_in[5];
    const float* w_v      = (const float*)d_in[6];
    const float* b_v      = (const float*)d_in[7];
    const float* w_o      = (const float*)d_in[8];
    const float* b_o      = (const float*)d_in[9];
    const float* g2       = (const float*)d_in[10];
    const float* b2       = (const float*)d_in[11];
    const float* w_gate   = (const float*)d_in[12];
    const float* b_gate   = (const float*)d_in[13];
    const float* g3       = (const float*)d_in[14];
    const float* b3       = (const float*)d_in[15];
    float* out = (float*)d_out;

    char* ws = (char*)d_ws;
    int8_t* Aq  = (int8_t*)ws; ws += (size_t)NM * KC;          // 67.1 MB (i8 [h|ao])
    int8_t* PB  = (int8_t*)ws; ws += (size_t)DM * KC;          // 8.4 MB (packed i8 B)
    bf16* hbf = (bf16*)ws;    ws += (size_t)NM * DM * 2;       // 67.1 MB (bf16 h copy)
    uint8_t* gq = (uint8_t*)ws; ws += (size_t)NM * DM;         // 33.5 MB (u8 gate)
    float* muA = (float*)ws;  ws += (size_t)NM * 4;
    float* rA  = (float*)ws;  ws += (size_t)NM * 4;
    float* raw1 = (float*)ws; ws += (size_t)NBATCH * DM * 4;
    float* hc   = (float*)ws; ws += (size_t)NBATCH * DM * 4;
    float* raw2 = (float*)ws; ws += (size_t)NBATCH * DM * 4;
    float* attnv= (float*)ws; ws += (size_t)NBATCH * DM * 4;

    k_pack_i8<<<2048, 256, 0, stream>>>(w_gate, PB);
    k_dot<DG><<<DM / 4, 256, 0, stream>>>(h_change, w_proj, b_proj, raw1);
    k_ln_small<<<NBATCH, 256, 0, stream>>>(raw1, g1, b1, hc);
    k_dot<DM><<<DM / 4, 256, 0, stream>>>(hc, w_v, b_v, raw2);
    k_dot<DM><<<DM / 4, 256, 0, stream>>>(raw2, w_o, b_o, attnv);
    k_stats_pack<<<NM, 256, 0, stream>>>(h_llm, attnv, g2, b2, Aq, hbf, muA, rA);
    k_gemm256<<<512, 512, 0, stream>>>(Aq, PB, b_gate, gq);
    k_epilogue<<<NM, 256, 0, stream>>>(hbf, gq, attnv, muA, rA, g2, b2, g3, b3, out);
}

// Round 9
// 236.370 us; speedup vs baseline: 1.2125x; 1.2125x over previous
//
#include <hip/hip_runtime.h>
#include <hip/hip_bf16.h>
#include <cstdint>
#include <cstddef>

#define DM 2048
#define DG 512
#define NBATCH 4
#define NT 4096
#define NM (NBATCH*NT)     // 16384 rows
#define KC (2*DM)          // 4096 concat-K (i8 elems = bytes)
#define LN_EPS 1e-5f
#define NTILES (KC/128)    // 32 K-tiles of BK=128 i8
#define SCL_A 16.0f        // qA = rint(x*16), covers |x|<=7.94
#define SCL_B 8192.0f      // qB = rint(w*8192), covers |w|<=0.0155
#define DESCALE (1.0f/131072.0f)   // 1/(SCL_A*SCL_B)
#define INV_SCL_A 0.0625f  // 1/SCL_A

typedef __bf16 bf16;
typedef bf16 bf16x8 __attribute__((ext_vector_type(8)));
typedef float f32x4 __attribute__((ext_vector_type(4)));
typedef int   i32x4 __attribute__((ext_vector_type(4)));
typedef char  i8x8  __attribute__((ext_vector_type(8)));
typedef unsigned char u8x8 __attribute__((ext_vector_type(8)));

#define AS1 __attribute__((address_space(1)))
#define AS3 __attribute__((address_space(3)))

__device__ __forceinline__ char q8(float x, float s) {
    int v = (int)rintf(x * s);
    v = v > 127 ? 127 : (v < -127 ? -127 : v);
    return (char)v;
}

// ---------- block-wide sum reduction of two scalars (blockDim.x == 256) ----------
__device__ __forceinline__ void block_reduce_2(float& s, float& s2) {
#pragma unroll
    for (int off = 32; off; off >>= 1) {
        s  += __shfl_down(s, off);
        s2 += __shfl_down(s2, off);
    }
    __shared__ float sm[8];
    const int wid = threadIdx.x >> 6, lane = threadIdx.x & 63;
    if (lane == 0) { sm[wid] = s; sm[4 + wid] = s2; }
    __syncthreads();
    s  = sm[0] + sm[1] + sm[2] + sm[3];
    s2 = sm[4] + sm[5] + sm[6] + sm[7];
}

// ---------- fused: blocks [0,512) = GEMV proj (dot<DG>); blocks [512,4608) = w_gate->i8 ----------
__global__ void k_pack_dot1(const float* __restrict__ wg, int8_t* __restrict__ wqb,
                            const float* __restrict__ X, const float* __restrict__ W,
                            const float* __restrict__ bias, float* __restrict__ out) {
    if (blockIdx.x >= 512) {
        const int i = (blockIdx.x - 512) * 256 + threadIdx.x;   // 1,048,576 units of 8
        const f32x4* s = (const f32x4*)wg + (size_t)i * 2;
        f32x4 a = s[0], b = s[1];
        i8x8 o;
#pragma unroll
        for (int q = 0; q < 4; q++) { o[q] = q8(a[q], SCL_B); o[4+q] = q8(b[q], SCL_B); }
        *((i8x8*)wqb + i) = o;
        return;
    }
    const int lane = threadIdx.x & 63;
    const int wid  = threadIdx.x >> 6;
    const int j = blockIdx.x * 4 + wid;
    const f32x4* Wr = (const f32x4*)(W + (size_t)j * DG);
    float acc[NBATCH] = {0.f, 0.f, 0.f, 0.f};
    constexpr int C = DG / 4 / 64;
#pragma unroll
    for (int i = 0; i < C; i++) {
        f32x4 wv = Wr[lane + 64 * i];
#pragma unroll
        for (int b = 0; b < NBATCH; b++) {
            f32x4 xv = ((const f32x4*)(X + (size_t)b * DG))[lane + 64 * i];
            acc[b] += wv[0]*xv[0] + wv[1]*xv[1] + wv[2]*xv[2] + wv[3]*xv[3];
        }
    }
#pragma unroll
    for (int off = 32; off; off >>= 1)
#pragma unroll
        for (int b = 0; b < NBATCH; b++) acc[b] += __shfl_down(acc[b], off);
    if (lane == 0) {
        const float bb = bias[j];
#pragma unroll
        for (int b = 0; b < NBATCH; b++) out[(size_t)b * DM + j] = acc[b] + bb;
    }
}

// ---------- small GEMV: out[b][j] = dot(X[b,:K], W[j,:K]) + bias[j] ----------
template<int K>
__global__ void k_dot(const float* __restrict__ X, const float* __restrict__ W,
                      const float* __restrict__ bias, float* __restrict__ out) {
    const int lane = threadIdx.x & 63;
    const int wid  = threadIdx.x >> 6;
    const int j = blockIdx.x * 4 + wid;
    const f32x4* Wr = (const f32x4*)(W + (size_t)j * K);
    float acc[NBATCH] = {0.f, 0.f, 0.f, 0.f};
    constexpr int C = K / 4 / 64;
#pragma unroll
    for (int i = 0; i < C; i++) {
        f32x4 wv = Wr[lane + 64 * i];
#pragma unroll
        for (int b = 0; b < NBATCH; b++) {
            f32x4 xv = ((const f32x4*)(X + (size_t)b * K))[lane + 64 * i];
            acc[b] += wv[0]*xv[0] + wv[1]*xv[1] + wv[2]*xv[2] + wv[3]*xv[3];
        }
    }
#pragma unroll
    for (int off = 32; off; off >>= 1)
#pragma unroll
        for (int b = 0; b < NBATCH; b++) acc[b] += __shfl_down(acc[b], off);
    if (lane == 0) {
        const float bb = bias[j];
#pragma unroll
        for (int b = 0; b < NBATCH; b++) out[(size_t)b * DM + j] = acc[b] + bb;
    }
}

// ---------- LN over rows of [NBATCH][DM] ----------
__global__ void k_ln_small(const float* __restrict__ in, const float* __restrict__ g,
                           const float* __restrict__ bt, float* __restrict__ out) {
    const int row = blockIdx.x;
    const int tid = threadIdx.x;
    const f32x4* ir = (const f32x4*)(in + (size_t)row * DM);
    f32x4 v0 = ir[tid], v1 = ir[tid + 256];
    float s  = v0[0]+v0[1]+v0[2]+v0[3] + v1[0]+v1[1]+v1[2]+v1[3];
    float s2 = v0[0]*v0[0]+v0[1]*v0[1]+v0[2]*v0[2]+v0[3]*v0[3]
             + v1[0]*v1[0]+v1[1]*v1[1]+v1[2]*v1[2]+v1[3]*v1[3];
    block_reduce_2(s, s2);
    const float mu = s * (1.0f / DM);
    const float r  = rsqrtf(s2 * (1.0f / DM) - mu * mu + LN_EPS);
    f32x4 g0 = ((const f32x4*)g)[tid],  g1v = ((const f32x4*)g)[tid + 256];
    f32x4 b0 = ((const f32x4*)bt)[tid], b1v = ((const f32x4*)bt)[tid + 256];
    f32x4 o0 = (v0 - mu) * r * g0 + b0;
    f32x4 o1 = (v1 - mu) * r * g1v + b1v;
    f32x4* orow = (f32x4*)(out + (size_t)row * DM);
    orow[tid] = o0; orow[tid + 256] = o1;
}

// ---------- per-row stats of (h+attn); write i8 [h | attn_out] only ----------
__global__ void k_stats_pack(const float* __restrict__ h, const float* __restrict__ attnv,
                             const float* __restrict__ g2, const float* __restrict__ b2,
                             int8_t* __restrict__ Aq,
                             float* __restrict__ muA, float* __restrict__ rA) {
    const int m = blockIdx.x;
    const int b = m >> 12;
    const int tid = threadIdx.x;          // thread covers elems [8*tid, 8*tid+8)
    const f32x4* hr = (const f32x4*)(h + (size_t)m * DM);
    const f32x4* ar = (const f32x4*)(attnv + (size_t)b * DM);
    f32x4 h0 = hr[2*tid], h1 = hr[2*tid + 1];
    f32x4 a0 = ar[2*tid], a1 = ar[2*tid + 1];
    f32x4 x0 = h0 + a0, x1 = h1 + a1;
    float s  = x0[0]+x0[1]+x0[2]+x0[3] + x1[0]+x1[1]+x1[2]+x1[3];
    float s2 = x0[0]*x0[0]+x0[1]*x0[1]+x0[2]*x0[2]+x0[3]*x0[3]
             + x1[0]*x1[0]+x1[1]*x1[1]+x1[2]*x1[2]+x1[3]*x1[3];
    block_reduce_2(s, s2);
    const float mu = s * (1.0f / DM);
    const float r  = rsqrtf(s2 * (1.0f / DM) - mu * mu + LN_EPS);
    if (tid == 0) { muA[m] = mu; rA[m] = r; }
    f32x4 gg0 = ((const f32x4*)g2)[2*tid], gg1 = ((const f32x4*)g2)[2*tid + 1];
    f32x4 bb0 = ((const f32x4*)b2)[2*tid], bb1 = ((const f32x4*)b2)[2*tid + 1];
    f32x4 ao0 = (x0 - mu) * r * gg0 + bb0;
    f32x4 ao1 = (x1 - mu) * r * gg1 + bb1;
    i8x8 qh, qa;
#pragma unroll
    for (int q = 0; q < 4; q++) {
        qh[q] = q8(h0[q], SCL_A);  qh[4+q] = q8(h1[q], SCL_A);
        qa[q] = q8(ao0[q], SCL_A); qa[4+q] = q8(ao1[q], SCL_A);
    }
    *(i8x8*)(Aq + (size_t)m * KC + 8*tid) = qh;
    *(i8x8*)(Aq + (size_t)m * KC + DM + 8*tid) = qa;
}

// ---------- 256x256 i8 MFMA GEMM (r7, best-measured): 1 barrier/tile, free VM(0) ----------
#define MF(a,b,c) __builtin_amdgcn_mfma_i32_16x16x64_i8(a,b,c,0,0,0)
#define SCHED0() __builtin_amdgcn_sched_barrier(0)
#define BAR()  { SCHED0(); asm volatile("s_barrier" ::: "memory"); SCHED0(); }
#define VM(n)  { asm volatile("s_waitcnt vmcnt(" #n ")" ::: "memory"); SCHED0(); }
#define LGKM(n) { asm volatile("s_waitcnt lgkmcnt(" #n ")" ::: "memory"); SCHED0(); }

__global__ __launch_bounds__(512, 2) void k_gemm256(const int8_t* __restrict__ A, const int8_t* __restrict__ Bw,
                                                    const float* __restrict__ bgate, uint8_t* __restrict__ gq) {
    __shared__ __align__(128) char smem[131072];   // [2 bufs][A 32KB | B 32KB]
    const int tid  = threadIdx.x;
    const int lane = tid & 63;
    const int wid  = tid >> 6;
    const int wm   = wid >> 2, wn = wid & 3;

    // bijective XCD swizzle: 512 blocks, 8 XCDs
    const int swz = (blockIdx.x & 7) * 64 + (blockIdx.x >> 3);
    const int bm = (swz >> 3) << 8;
    const int bn = (swz & 7) << 8;

    // staging: inverse-swizzled global source (bytes), linear LDS dest
    const int r_local = tid >> 3;                 // row within a 64-row round
    const int sc = (tid & 7) ^ (r_local & 7);     // swizzled 16B chunk
    const int8_t* Abase = A  + (size_t)(bm + r_local) * KC + sc*16;
    const int8_t* Bbase = Bw + (size_t)(bn + r_local) * KC + sc*16;
    const int ldsW = wid << 10;

#define STAGEA(buf, rnd, kt) __builtin_amdgcn_global_load_lds( \
        (const AS1 void*)(Abase + (size_t)(rnd)*64*KC + (kt)*128), \
        (AS3 void*)(smem + (buf)*65536 + (rnd)*8192 + ldsW), 16, 0, 0)
#define STAGEB(buf, rnd, kt) __builtin_amdgcn_global_load_lds( \
        (const AS1 void*)(Bbase + (size_t)(rnd)*64*KC + (kt)*128), \
        (AS3 void*)(smem + (buf)*65536 + 32768 + (rnd)*8192 + ldsW), 16, 0, 0)

    // fragment read byte offsets (swizzled); rows are 128B
    const int co0 = ((lane >> 4) ^ (lane & 7)) << 4;         // ks=0: chunks 0-3
    const int co1 = ((4 + (lane >> 4)) ^ (lane & 7)) << 4;   // ks=1: chunks 4-7
    const int arowb = (wm*128 + (lane & 15)) * 128;
    const int browb = (wn*64  + (lane & 15)) * 128;

#define AFRG(buf, m, ks) (*(const i32x4*)(smem + (buf)*65536 + arowb + (m)*2048 + ((ks) ? co1 : co0)))
#define BFRG(buf, n, ks) (*(const i32x4*)(smem + (buf)*65536 + 32768 + browb + (n)*2048 + ((ks) ? co1 : co0)))

    i32x4 acc[8][4] = {};
    i32x4 aLo[4][2], aHi[4][2], b01[2][2], b23[2][2];

#define LOAD_ALO(buf) { _Pragma("unroll") for (int i = 0; i < 4; i++) { aLo[i][0] = AFRG(buf,i,0);   aLo[i][1] = AFRG(buf,i,1);   } }
#define LOAD_AHI(buf) { _Pragma("unroll") for (int i = 0; i < 4; i++) { aHi[i][0] = AFRG(buf,4+i,0); aHi[i][1] = AFRG(buf,4+i,1); } }
#define LOAD_B01(buf) { _Pragma("unroll") for (int j = 0; j < 2; j++) { b01[j][0] = BFRG(buf,j,0);   b01[j][1] = BFRG(buf,j,1);   } }
#define LOAD_B23(buf) { _Pragma("unroll") for (int j = 0; j < 2; j++) { b23[j][0] = BFRG(buf,2+j,0); b23[j][1] = BFRG(buf,2+j,1); } }

#define MMQ(MOFF, AF, BF, NOFF) { _Pragma("unroll") for (int i = 0; i < 4; i++) \
        _Pragma("unroll") for (int j = 0; j < 2; j++) { \
            acc[(MOFF)+i][(NOFF)+j] = MF(AF[i][0], BF[j][0], acc[(MOFF)+i][(NOFF)+j]); \
            acc[(MOFF)+i][(NOFF)+j] = MF(AF[i][1], BF[j][1], acc[(MOFF)+i][(NOFF)+j]); } }

    // ---- prologue: tile 0 -> buf0, full drain once
    STAGEB(0,0,0); STAGEB(0,1,0); STAGEB(0,2,0); STAGEB(0,3,0);
    STAGEA(0,0,0); STAGEA(0,2,0); STAGEA(0,1,0); STAGEA(0,3,0);
    VM(0);
    BAR();

#define TILE_BODY(TT, BUF, NBUF) { \
    const bool g = (TT) < NTILES - 1; \
    /* P0: stage B0-3(T+1); issue 16 reads (aLo,b01 + b23 ahead); Q0 */ \
    if (g) { STAGEB(NBUF,0,(TT)+1); STAGEB(NBUF,1,(TT)+1); STAGEB(NBUF,2,(TT)+1); STAGEB(NBUF,3,(TT)+1); } \
    LOAD_ALO(BUF); LOAD_B01(BUF); LOAD_B23(BUF); SCHED0(); \
    LGKM(4); \
    __builtin_amdgcn_s_setprio(1); \
    MMQ(0, aLo, b01, 0); \
    __builtin_amdgcn_s_setprio(0); SCHED0(); \
    /* P1: stage A0-3(T+1); issue aHi ahead; Q1 */ \
    if (g) { STAGEA(NBUF,0,(TT)+1); STAGEA(NBUF,1,(TT)+1); STAGEA(NBUF,2,(TT)+1); STAGEA(NBUF,3,(TT)+1); } \
    LOAD_AHI(BUF); SCHED0(); \
    LGKM(8); \
    __builtin_amdgcn_s_setprio(1); \
    MMQ(0, aLo, b23, 2); \
    __builtin_amdgcn_s_setprio(0); SCHED0(); \
    /* P2: Q2 (aHi drained under Q1) */ \
    LGKM(0); \
    __builtin_amdgcn_s_setprio(1); \
    MMQ(4, aHi, b23, 2); \
    __builtin_amdgcn_s_setprio(0); SCHED0(); \
    /* P3: Q3 (b01 still live); free VM(0) (stages landed under Q1-Q3); BAR */ \
    __builtin_amdgcn_s_setprio(1); \
    MMQ(4, aHi, b01, 0); \
    __builtin_amdgcn_s_setprio(0); SCHED0(); \
    VM(0); \
    BAR(); \
}

    for (int T = 0; T < NTILES; T += 2) {
        TILE_BODY(T,   0, 1);
        TILE_BODY(T+1, 1, 0);
    }

    // ---- epilogue: gate = sigmoid(acc*DESCALE + bias) -> u8
#pragma unroll
    for (int n = 0; n < 4; n++) {
        const int col = bn + wn*64 + n*16 + (lane & 15);
        const float bg = bgate[col];
#pragma unroll
        for (int m = 0; m < 8; m++) {
            const int row = bm + wm*128 + m*16 + ((lane >> 4) << 2);
#pragma unroll
            for (int r = 0; r < 4; r++) {
                const float z = (float)acc[m][n][r] * DESCALE + bg;
                const float gate = 1.0f / (1.0f + __expf(-z));
                gq[(size_t)(row + r) * DM + col] = (uint8_t)(int)rintf(gate * 255.0f);
            }
        }
    }
}

// ---------- epilogue: blend with u8 gate + i8 h (from Aq), LN3 per row ----------
__global__ void k_epilogue(const int8_t* __restrict__ Aq, const uint8_t* __restrict__ gq,
                           const float* __restrict__ attnv, const float* __restrict__ muA,
                           const float* __restrict__ rA,
                           const float* __restrict__ g2, const float* __restrict__ b2,
                           const float* __restrict__ g3, const float* __restrict__ b3,
                           float* __restrict__ out) {
    const int m = blockIdx.x;
    const int b = m >> 12;
    const int tid = threadIdx.x;          // thread handles elems [8*tid, 8*tid+8)
    i8x8 qh = *(const i8x8*)(Aq + (size_t)m * KC + 8*tid);
    f32x4 h0, h1;
#pragma unroll
    for (int q = 0; q < 4; q++) { h0[q] = (float)qh[q] * INV_SCL_A; h1[q] = (float)qh[4+q] * INV_SCL_A; }
    const f32x4* ar = (const f32x4*)(attnv + (size_t)b * DM);
    f32x4 a0 = ar[2*tid], a1 = ar[2*tid + 1];
    const float mu = muA[m];
    const float r  = rA[m];
    f32x4 gg0 = ((const f32x4*)g2)[2*tid], gg1 = ((const f32x4*)g2)[2*tid + 1];
    f32x4 bb0 = ((const f32x4*)b2)[2*tid], bb1 = ((const f32x4*)b2)[2*tid + 1];
    f32x4 ao0 = (h0 + a0 - mu) * r * gg0 + bb0;
    f32x4 ao1 = (h1 + a1 - mu) * r * gg1 + bb1;
    u8x8 qv = *(const u8x8*)(gq + (size_t)m * DM + 8*tid);
    f32x4 gt0, gt1;
#pragma unroll
    for (int q = 0; q < 4; q++) {
        gt0[q] = (float)qv[q]   * (1.0f / 255.0f);
        gt1[q] = (float)qv[4+q] * (1.0f / 255.0f);
    }
    f32x4 f0 = h0 + gt0 * (ao0 - h0);
    f32x4 f1 = h1 + gt1 * (ao1 - h1);
    float s  = f0[0]+f0[1]+f0[2]+f0[3] + f1[0]+f1[1]+f1[2]+f1[3];
    float s2 = f0[0]*f0[0]+f0[1]*f0[1]+f0[2]*f0[2]+f0[3]*f0[3]
             + f1[0]*f1[0]+f1[1]*f1[1]+f1[2]*f1[2]+f1[3]*f1[3];
    block_reduce_2(s, s2);
    const float mu3 = s * (1.0f / DM);
    const float r3  = rsqrtf(s2 * (1.0f / DM) - mu3 * mu3 + LN_EPS);
    f32x4 g30 = ((const f32x4*)g3)[2*tid], g31 = ((const f32x4*)g3)[2*tid + 1];
    f32x4 b30 = ((const f32x4*)b3)[2*tid], b31 = ((const f32x4*)b3)[2*tid + 1];
    f32x4 o0 = (f0 - mu3) * r3 * g30 + b30;
    f32x4 o1 = (f1 - mu3) * r3 * g31 + b31;
    f32x4* orow = (f32x4*)(out + (size_t)m * DM);
    orow[2*tid] = o0; orow[2*tid + 1] = o1;
}

extern "C" void kernel_launch(void* const* d_in, const int* in_sizes, int n_in,
                              void* d_out, int out_size, void* d_ws, size_t ws_size,
                              hipStream_t stream) {
    const float* h_llm    = (const float*)d_in[0];
    const float* h_change = (const float*)d_in[1];
    const float* w_proj   = (const float*)d_in[2];
    const float* b_proj   = (const float*)d_in[3];
    const float* g1       = (const float*)d_in[4];
    const float* b1       = (const float*)d_in[5];
    const float* w_v      = (const float*)d_in[6];
    const float* b_v      = (const float*)d_in[7];
    const float* w_o      = (const float*)d_in[8];
    const float* b_o      = (const float*)d_in[9];
    const float* g2       = (const float*)d_in[10];
    const float* b2       = (const float*)d_in[11];
    const float* w_gate   = (const float*)d_in[12];
    const float* b_gate   = (const float*)d_in[13];
    const float* g3       = (const float*)d_in[14];
    const float* b3       = (const float*)d_in[15];
    float* out = (float*)d_out;

    char* ws = (char*)d_ws;
    int8_t* Aq  = (int8_t*)ws; ws += (size_t)NM * KC;          // 67.1 MB (i8 [h|ao])
    int8_t* wqb = (int8_t*)ws; ws += (size_t)DM * KC;          // 8.4 MB (i8 weights)
    uint8_t* gq = (uint8_t*)ws; ws += (size_t)NM * DM;         // 33.5 MB (u8 gate)
    float* muA = (float*)ws;  ws += (size_t)NM * 4;
    float* rA  = (float*)ws;  ws += (size_t)NM * 4;
    float* raw1 = (float*)ws; ws += (size_t)NBATCH * DM * 4;
    float* hc   = (float*)ws; ws += (size_t)NBATCH * DM * 4;
    float* raw2 = (float*)ws; ws += (size_t)NBATCH * DM * 4;
    float* attnv= (float*)ws; ws += (size_t)NBATCH * DM * 4;

    // proj GEMV (blocks 0-511) + w_gate i8 quantize (blocks 512-4607) in one launch
    k_pack_dot1<<<4608, 256, 0, stream>>>(w_gate, wqb, h_change, w_proj, b_proj, raw1);
    k_ln_small<<<NBATCH, 256, 0, stream>>>(raw1, g1, b1, hc);
    k_dot<DM><<<DM / 4, 256, 0, stream>>>(hc, w_v, b_v, raw2);
    k_dot<DM><<<DM / 4, 256, 0, stream>>>(raw2, w_o, b_o, attnv);
    k_stats_pack<<<NM, 256, 0, stream>>>(h_llm, attnv, g2, b2, Aq, muA, rA);
    k_gemm256<<<512, 512, 0, stream>>>(Aq, wqb, b_gate, gq);
    k_epilogue<<<NM, 256, 0, stream>>>(Aq, gq, attnv, muA, rA, g2, b2, g3, b3, out);
}